// Round 1
// baseline (47.115 us; speedup 1.0000x reference)
//
#include <hip/hip_runtime.h>
#include <math.h>

#define BLOCK 256
#define NB 8   // batch elements per block; grid = 8192/NB = 1024

__global__ __launch_bounds__(BLOCK) void quanv_fused_kernel(
    const float* __restrict__ x,          // (8192,1,28,28)
    const float* __restrict__ conv_w,     // (4,1,2,2)
    const float* __restrict__ conv_b,     // (4)
    const float* __restrict__ bn_gamma,   // (4)
    const float* __restrict__ bn_beta,    // (4)
    const float* __restrict__ bn_mean,    // (4)
    const float* __restrict__ bn_var,     // (4)
    const float* __restrict__ sw_p,       // scalar
    const float* __restrict__ theta,      // (8)
    const float* __restrict__ lin_w,      // (10,784)
    const float* __restrict__ lin_b,      // (10)
    const float* __restrict__ log_scale_p,// scalar
    float* __restrict__ out)              // (8192,10)
{
    __shared__ float lw[10 * 784];   // 31360 B
    __shared__ float xs[784];        // one image
    __shared__ float qf[784];        // quantum features, index p*4+q
    __shared__ float scb[784];       // shortcut features, index c*196+p
    __shared__ float red[4][10];     // per-wave partial logits

    const int t = threadIdx.x;

    // stage lin_w into LDS once per block
    for (int i = t; i < 7840; i += BLOCK) lw[i] = lin_w[i];

    // ---- per-thread constant setup (broadcast loads, L1-hit) ----
    const float sw = sw_p[0];
    const float ls = log_scale_p[0];

    // fold conv + BN + shortcut_weight:  feat_sc = sw*(BN(conv(x)))
    float wf[4][4], bf[4];
#pragma unroll
    for (int c = 0; c < 4; ++c) {
        float scale = bn_gamma[c] * rsqrtf(bn_var[c] + 1e-5f);
        float sws = sw * scale;
#pragma unroll
        for (int k = 0; k < 4; ++k) wf[c][k] = sws * conv_w[c * 4 + k];
        bf[c] = sw * (scale * (conv_b[c] - bn_mean[c]) + bn_beta[c]);
    }

    float th0 = theta[0], th1 = theta[1], th2 = theta[2], th3 = theta[3];
    float s4, c4, s5, c5, s6, c6, s7, c7;
    __sincosf(0.5f * theta[4], &s4, &c4);
    __sincosf(0.5f * theta[5], &s5, &c5);
    __sincosf(0.5f * theta[6], &s6, &c6);
    __sincosf(0.5f * theta[7], &s7, &c7);

    const int b0 = blockIdx.x * NB;

    for (int nb = 0; nb < NB; ++nb) {
        const int b = b0 + nb;
        __syncthreads();  // protect xs/qf/scb from previous iteration readers

        const float* xb = x + (size_t)b * 784;
        for (int i = t; i < 784; i += BLOCK) xs[i] = xb[i];
        __syncthreads();

        // ---- one 2x2 patch per thread (196 patches) ----
        if (t < 196) {
            const int p = t;
            const int i = p / 14, j = p % 14;
            const float x00 = xs[(2 * i) * 28 + 2 * j];
            const float x01 = xs[(2 * i) * 28 + 2 * j + 1];
            const float x10 = xs[(2 * i + 1) * 28 + 2 * j];
            const float x11 = xs[(2 * i + 1) * 28 + 2 * j + 1];

            // pair (wire0,wire1): pixels x00,x01; thetas th0,th1 / th4,th5
            float m0, m1, m2, m3;
            {
                float sA, cA, sB, cB;
                __sincosf(0.5f * (x00 + th0), &sA, &cA);
                __sincosf(0.5f * (x01 + th1), &sB, &cB);
                float u0 = c4 * cA * cB - s4 * sA * sB;
                float u1 = c4 * cA * sB - s4 * sA * cB;
                float u2 = s4 * cA * cB + c4 * sA * sB;
                float u3 = s4 * cA * sB + c4 * sA * cB;
                float v0 = c5 * u0 - s5 * u1;
                float v1 = s5 * u0 + c5 * u1;
                float v2 = c5 * u2 - s5 * u3;
                float v3 = s5 * u2 + c5 * u3;
                m0 = u0 * u0 + u1 * u1 - u2 * u2 - u3 * u3;
                m1 = v0 * v0 - v1 * v1 + v2 * v2 - v3 * v3;
            }
            // pair (wire2,wire3): pixels x10,x11; thetas th2,th3 / th6,th7
            {
                float sA, cA, sB, cB;
                __sincosf(0.5f * (x10 + th2), &sA, &cA);
                __sincosf(0.5f * (x11 + th3), &sB, &cB);
                float u0 = c6 * cA * cB - s6 * sA * sB;
                float u1 = c6 * cA * sB - s6 * sA * cB;
                float u2 = s6 * cA * cB + c6 * sA * sB;
                float u3 = s6 * cA * sB + c6 * sA * cB;
                float v0 = c7 * u0 - s7 * u1;
                float v1 = s7 * u0 + c7 * u1;
                float v2 = c7 * u2 - s7 * u3;
                float v3 = s7 * u2 + c7 * u3;
                m2 = u0 * u0 + u1 * u1 - u2 * u2 - u3 * u3;
                m3 = v0 * v0 - v1 * v1 + v2 * v2 - v3 * v3;
            }
            qf[p * 4 + 0] = m0;
            qf[p * 4 + 1] = m1;
            qf[p * 4 + 2] = m2;
            qf[p * 4 + 3] = m3;
#pragma unroll
            for (int c = 0; c < 4; ++c)
                scb[c * 196 + p] = wf[c][0] * x00 + wf[c][1] * x01 +
                                   wf[c][2] * x10 + wf[c][3] * x11 + bf[c];
        }
        __syncthreads();

        // ---- 784 x 10 matmul: each thread covers f = t, t+256, ... ----
        float acc[10];
#pragma unroll
        for (int k = 0; k < 10; ++k) acc[k] = 0.f;
        for (int f = t; f < 784; f += BLOCK) {
            const float v = qf[f] + scb[f];
#pragma unroll
            for (int k = 0; k < 10; ++k) acc[k] += v * lw[k * 784 + f];
        }
        // wave-level reduce (64 lanes)
#pragma unroll
        for (int k = 0; k < 10; ++k)
            for (int off = 32; off; off >>= 1)
                acc[k] += __shfl_down(acc[k], off);
        const int wave = t >> 6, lane = t & 63;
        if (lane == 0) {
#pragma unroll
            for (int k = 0; k < 10; ++k) red[wave][k] = acc[k];
        }
        __syncthreads();

        if (t == 0) {
            float logits[10], m = -1e30f;
#pragma unroll
            for (int k = 0; k < 10; ++k) {
                float v = (red[0][k] + red[1][k] + red[2][k] + red[3][k] +
                           lin_b[k]) * ls;
                logits[k] = v;
                m = fmaxf(m, v);
            }
            float s = 0.f;
#pragma unroll
            for (int k = 0; k < 10; ++k) s += __expf(logits[k] - m);
            const float lse = m + __logf(s);
            float* ob = out + (size_t)b * 10;
#pragma unroll
            for (int k = 0; k < 10; ++k) ob[k] = logits[k] - lse;
        }
    }
}

extern "C" void kernel_launch(void* const* d_in, const int* in_sizes, int n_in,
                              void* d_out, int out_size, void* d_ws, size_t ws_size,
                              hipStream_t stream) {
    const float* x         = (const float*)d_in[0];
    const float* conv_w    = (const float*)d_in[1];
    const float* conv_b    = (const float*)d_in[2];
    const float* bn_gamma  = (const float*)d_in[3];
    const float* bn_beta   = (const float*)d_in[4];
    const float* bn_mean   = (const float*)d_in[5];
    const float* bn_var    = (const float*)d_in[6];
    const float* sw        = (const float*)d_in[7];
    const float* theta     = (const float*)d_in[8];
    const float* lin_w     = (const float*)d_in[9];
    const float* lin_b     = (const float*)d_in[10];
    const float* log_scale = (const float*)d_in[11];
    float* out = (float*)d_out;

    const int B = 8192;
    dim3 grid(B / NB), block(BLOCK);
    hipLaunchKernelGGL(quanv_fused_kernel, grid, block, 0, stream,
                       x, conv_w, conv_b, bn_gamma, bn_beta, bn_mean, bn_var,
                       sw, theta, lin_w, lin_b, log_scale, out);
}

// Round 2
// 19.992 us; speedup vs baseline: 2.3567x; 2.3567x over previous
//
#include <hip/hip_runtime.h>
#include <hip/hip_fp16.h>
#include <math.h>

#define BLOCK 256
#define WAVES 4
#define IPW   2          // images per wave
#define LWS   792        // lin_w LDS row stride in halves (padded, 16B-aligned rows)
#define FEATS 792        // per-wave feature buffer (halves)

typedef _Float16 h2v __attribute__((ext_vector_type(2)));

__device__ __forceinline__ float dot2h(unsigned a, unsigned b, float c) {
#if __has_builtin(__builtin_amdgcn_fdot2)
    return __builtin_amdgcn_fdot2(__builtin_bit_cast(h2v, a),
                                  __builtin_bit_cast(h2v, b), c, false);
#else
    h2v xa = __builtin_bit_cast(h2v, a), yb = __builtin_bit_cast(h2v, b);
    return c + (float)xa[0] * (float)yb[0] + (float)xa[1] * (float)yb[1];
#endif
}

__device__ __forceinline__ unsigned packh(float a, float b) {
    __half2 h = __float22half2_rn(make_float2(a, b));
    return __builtin_bit_cast(unsigned, h);
}

__global__ __launch_bounds__(BLOCK) void quanv_fused2(
    const float* __restrict__ x,
    const float* __restrict__ conv_w,
    const float* __restrict__ conv_b,
    const float* __restrict__ bn_gamma,
    const float* __restrict__ bn_beta,
    const float* __restrict__ bn_mean,
    const float* __restrict__ bn_var,
    const float* __restrict__ sw_p,
    const float* __restrict__ theta,
    const float* __restrict__ lin_w,
    const float* __restrict__ lin_b,
    const float* __restrict__ log_scale_p,
    float* __restrict__ out)
{
    __shared__ __half lw[10 * LWS];          // 15840 B
    __shared__ __half feat[WAVES][FEATS];    //  6336 B

    const int t = threadIdx.x;
    const int lane = t & 63, wv = t >> 6;
    __half* fw = &feat[wv][0];

    // ---- stage lin_w into LDS as fp16 (padded rows) ----
    for (int g = t * 4; g < 7840; g += BLOCK * 4) {
        float4 v = *(const float4*)(lin_w + g);
        int k = g / 784, f = g - k * 784;       // f % 4 == 0 -> stays in one row
        uint2 pk;
        pk.x = packh(v.x, v.y);
        pk.y = packh(v.z, v.w);
        *(uint2*)&lw[k * LWS + f] = pk;
    }

    // ---- per-thread constants ----
    const float sw = sw_p[0];
    const float ls = log_scale_p[0];
    float wf[4][4], bf[4];
#pragma unroll
    for (int c = 0; c < 4; ++c) {
        float scale = bn_gamma[c] * rsqrtf(bn_var[c] + 1e-5f);
        float sws = sw * scale;
#pragma unroll
        for (int k = 0; k < 4; ++k) wf[c][k] = sws * conv_w[c * 4 + k];
        bf[c] = sw * (scale * (conv_b[c] - bn_mean[c]) + bn_beta[c]);
    }
    const float th0 = theta[0], th1 = theta[1], th2 = theta[2], th3 = theta[3];
    float s4, c4, s5, c5, s6, c6, s7, c7;
    __sincosf(0.5f * theta[4], &s4, &c4);
    __sincosf(0.5f * theta[5], &s5, &c5);
    __sincosf(0.5f * theta[6], &s6, &c6);
    __sincosf(0.5f * theta[7], &s7, &c7);

    // quantum 2-qubit-pair measurement: inputs two pixels -> m[0],m[1] (or m[2],m[3])
    auto pair_meas = [&](float xa, float xb, float tha, float thb,
                         float sE, float cE, float sF, float cF,
                         float& mA, float& mB) {
        float sA, cA, sB, cB;
        __sincosf(0.5f * (xa + tha), &sA, &cA);
        __sincosf(0.5f * (xb + thb), &sB, &cB);
        float cc = cA * cB, ss = sA * sB, cs = cA * sB, sc_ = sA * cB;
        float u0 = cE * cc - sE * ss;
        float u1 = cE * cs - sE * sc_;
        float u2 = sE * cc + cE * ss;
        float u3 = sE * cs + cE * sc_;
        float v0 = cF * u0 - sF * u1, v1 = sF * u0 + cF * u1;
        float v2 = cF * u2 - sF * u3, v3 = sF * u2 + cF * u3;
        mA = u0 * u0 + u1 * u1 - u2 * u2 - u3 * u3;
        mB = v0 * v0 - v1 * v1 + v2 * v2 - v3 * v3;
    };

    float2 px[8];
    auto load_pix = [&](int img) {
        const float* xb = x + (size_t)img * 784;
#pragma unroll
        for (int j = 0; j < 4; ++j) {
            int p = lane + 64 * j; if (p > 195) p = 195;
            int i = p / 14, jj = p - i * 14;
            px[2 * j]     = *(const float2*)(xb + (2 * i) * 28 + 2 * jj);
            px[2 * j + 1] = *(const float2*)(xb + (2 * i + 1) * 28 + 2 * jj);
        }
    };

    const int img0 = (blockIdx.x * WAVES + wv) * IPW;
    load_pix(img0);

    for (int it = 0; it < IPW; ++it) {
        const int img = img0 + it;
        unsigned q0[4], q1[4];

        // ---- pass 1: patch math; write shortcut feats, keep quantum feats in regs
#pragma unroll
        for (int j = 0; j < 3; ++j) {
            const int p = lane + 64 * j;
            float x00 = px[2 * j].x, x01 = px[2 * j].y;
            float x10 = px[2 * j + 1].x, x11 = px[2 * j + 1].y;
            float m0, m1, m2, m3;
            pair_meas(x00, x01, th0, th1, s4, c4, s5, c5, m0, m1);
            pair_meas(x10, x11, th2, th3, s6, c6, s7, c7, m2, m3);
            q0[j] = packh(m0, m1);
            q1[j] = packh(m2, m3);
#pragma unroll
            for (int c = 0; c < 4; ++c)
                fw[c * 196 + p] = __float2half(
                    wf[c][0] * x00 + wf[c][1] * x01 +
                    wf[c][2] * x10 + wf[c][3] * x11 + bf[c]);
        }
        if (lane < 4) {
            const int p = lane + 192;
            float x00 = px[6].x, x01 = px[6].y;
            float x10 = px[7].x, x11 = px[7].y;
            float m0, m1, m2, m3;
            pair_meas(x00, x01, th0, th1, s4, c4, s5, c5, m0, m1);
            pair_meas(x10, x11, th2, th3, s6, c6, s7, c7, m2, m3);
            q0[3] = packh(m0, m1);
            q1[3] = packh(m2, m3);
#pragma unroll
            for (int c = 0; c < 4; ++c)
                fw[c * 196 + p] = __float2half(
                    wf[c][0] * x00 + wf[c][1] * x01 +
                    wf[c][2] * x10 + wf[c][3] * x11 + bf[c]);
        }

        // issue next image's pixel loads now; latency hides under pass2+matmul
        if (it + 1 < IPW) load_pix(img + 1);

        __syncthreads();   // sc slots complete (whole wave / block)

        // ---- pass 2: add quantum feats into their slots (each lane owns slots 4p..4p+3)
#pragma unroll
        for (int j = 0; j < 3; ++j) {
            const int p = lane + 64 * j;
            uint2 v = *(uint2*)&fw[4 * p];
            __half2 a0 = __builtin_bit_cast(__half2, v.x);
            __half2 a1 = __builtin_bit_cast(__half2, v.y);
            a0 = __hadd2(a0, __builtin_bit_cast(__half2, q0[j]));
            a1 = __hadd2(a1, __builtin_bit_cast(__half2, q1[j]));
            v.x = __builtin_bit_cast(unsigned, a0);
            v.y = __builtin_bit_cast(unsigned, a1);
            *(uint2*)&fw[4 * p] = v;
        }
        if (lane < 4) {
            const int p = lane + 192;
            uint2 v = *(uint2*)&fw[4 * p];
            __half2 a0 = __builtin_bit_cast(__half2, v.x);
            __half2 a1 = __builtin_bit_cast(__half2, v.y);
            a0 = __hadd2(a0, __builtin_bit_cast(__half2, q0[3]));
            a1 = __hadd2(a1, __builtin_bit_cast(__half2, q1[3]));
            v.x = __builtin_bit_cast(unsigned, a0);
            v.y = __builtin_bit_cast(unsigned, a1);
            *(uint2*)&fw[4 * p] = v;
        }

        __syncthreads();   // feat complete

        // ---- matmul: lane = k*6 + c ; k<10 ; chunk c of 784 feats
        float acc = 0.f;
        if (lane < 60) {
            const int k = lane / 6, c = lane - k * 6;
            const int start = c * 136;
            const int nit = (c == 5) ? 13 : 17;     // 104 or 136 feats, 8/iter
            const uint4* fp = (const uint4*)&fw[start];
            const uint4* wp = (const uint4*)&lw[k * LWS + start];
            for (int i = 0; i < nit; ++i) {
                uint4 a = fp[i], b = wp[i];
                acc = dot2h(a.x, b.x, acc);
                acc = dot2h(a.y, b.y, acc);
                acc = dot2h(a.z, b.z, acc);
                acc = dot2h(a.w, b.w, acc);
            }
        }
        // reduce over the 6 chunk lanes (valid at lane = 6k)
        float s1 = acc + __shfl_down(acc, 1);
        float s2 = s1 + __shfl_down(s1, 2);
        float tot = s2 + __shfl_down(s1, 4);

        float logit = 0.f;
        if (lane < 60 && lane % 6 == 0)
            logit = (tot + lin_b[lane / 6]) * ls;

        // gather 10 logits to every lane; redundant lse; lanes 0-9 store
        float m = -1e30f;
        float lg;
#pragma unroll
        for (int kk = 0; kk < 10; ++kk) {
            float v = __shfl(logit, kk * 6);
            m = fmaxf(m, v);
        }
        float ssum = 0.f;
#pragma unroll
        for (int kk = 0; kk < 10; ++kk) {
            float v = __shfl(logit, kk * 6);
            ssum += __expf(v - m);
        }
        const float lse = m + __logf(ssum);
        lg = __shfl(logit, 6 * lane);   // lane<10: its own logit
        if (lane < 10) out[(size_t)img * 10 + lane] = lg - lse;

        __syncthreads();   // feat consumed; safe to overwrite next iteration
    }
}

extern "C" void kernel_launch(void* const* d_in, const int* in_sizes, int n_in,
                              void* d_out, int out_size, void* d_ws, size_t ws_size,
                              hipStream_t stream) {
    const float* x         = (const float*)d_in[0];
    const float* conv_w    = (const float*)d_in[1];
    const float* conv_b    = (const float*)d_in[2];
    const float* bn_gamma  = (const float*)d_in[3];
    const float* bn_beta   = (const float*)d_in[4];
    const float* bn_mean   = (const float*)d_in[5];
    const float* bn_var    = (const float*)d_in[6];
    const float* sw        = (const float*)d_in[7];
    const float* theta     = (const float*)d_in[8];
    const float* lin_w     = (const float*)d_in[9];
    const float* lin_b     = (const float*)d_in[10];
    const float* log_scale = (const float*)d_in[11];
    float* out = (float*)d_out;

    const int B = in_sizes[0] / 784;           // 8192
    dim3 grid(B / (WAVES * IPW)), block(BLOCK);
    hipLaunchKernelGGL(quanv_fused2, grid, block, 0, stream,
                       x, conv_w, conv_b, bn_gamma, bn_beta, bn_mean, bn_var,
                       sw, theta, lin_w, lin_b, log_scale, out);
}

// Round 3
// 19.467 us; speedup vs baseline: 2.4202x; 1.0270x over previous
//
#include <hip/hip_runtime.h>
#include <hip/hip_fp16.h>
#include <math.h>

#define BLOCK 512
#define WVS   8          // waves per block
#define LWS   792        // lin_w LDS row stride in halves (16B-aligned rows)
#define FEATS 792        // per-image feature buffer (halves)

typedef _Float16 h2v __attribute__((ext_vector_type(2)));

__device__ __forceinline__ float dot2h(unsigned a, unsigned b, float c) {
#if __has_builtin(__builtin_amdgcn_fdot2)
    return __builtin_amdgcn_fdot2(__builtin_bit_cast(h2v, a),
                                  __builtin_bit_cast(h2v, b), c, false);
#else
    h2v xa = __builtin_bit_cast(h2v, a), yb = __builtin_bit_cast(h2v, b);
    return c + (float)xa[0] * (float)yb[0] + (float)xa[1] * (float)yb[1];
#endif
}

__device__ __forceinline__ unsigned packh(float a, float b) {
    __half2 h = __float22half2_rn(make_float2(a, b));
    return __builtin_bit_cast(unsigned, h);
}

#define WAVE_LGKM() asm volatile("s_waitcnt lgkmcnt(0)" ::: "memory")

__global__ __launch_bounds__(BLOCK, 4) void quanv_fused3(
    const float* __restrict__ x,
    const float* __restrict__ conv_w,
    const float* __restrict__ conv_b,
    const float* __restrict__ bn_gamma,
    const float* __restrict__ bn_beta,
    const float* __restrict__ bn_mean,
    const float* __restrict__ bn_var,
    const float* __restrict__ sw_p,
    const float* __restrict__ theta,
    const float* __restrict__ lin_w,
    const float* __restrict__ lin_b,
    const float* __restrict__ log_scale_p,
    float* __restrict__ out)
{
    __shared__ __half lw[10 * LWS];            // 15840 B
    __shared__ __half feat[WVS][2][FEATS];     // 25344 B

    const int t = threadIdx.x;
    const int lane = t & 63, wv = t >> 6;
    __half* fw0 = &feat[wv][0][0];
    __half* fw1 = &feat[wv][1][0];

    const int img0 = (blockIdx.x * WVS + wv) * 2;
    const int img1 = img0 + 1;

    // ---- issue both images' pixel loads first (critical path) ----
    float2 px0[8], px1[8];
    {
        const float* xb0 = x + (size_t)img0 * 784;
        const float* xb1 = x + (size_t)img1 * 784;
#pragma unroll
        for (int j = 0; j < 4; ++j) {
            int p = lane + 64 * j; if (p > 195) p = 195;
            int i = p / 14, jj = p - i * 14;
            const int o0 = (2 * i) * 28 + 2 * jj, o1 = o0 + 28;
            px0[2 * j]     = *(const float2*)(xb0 + o0);
            px0[2 * j + 1] = *(const float2*)(xb0 + o1);
            px1[2 * j]     = *(const float2*)(xb1 + o0);
            px1[2 * j + 1] = *(const float2*)(xb1 + o1);
        }
    }

    // ---- stage lin_w into LDS as fp16 (huge slack until the barrier) ----
    for (int g = t * 4; g < 7840; g += BLOCK * 4) {
        float4 v = *(const float4*)(lin_w + g);
        int k = g / 784, f = g - k * 784;
        uint2 pk;
        pk.x = packh(v.x, v.y);
        pk.y = packh(v.z, v.w);
        *(uint2*)&lw[k * LWS + f] = pk;
    }

    // ---- per-thread constants ----
    const float sw = sw_p[0];
    const float ls = log_scale_p[0];
    float wf[4][4], bf[4];
#pragma unroll
    for (int c = 0; c < 4; ++c) {
        float scale = bn_gamma[c] * rsqrtf(bn_var[c] + 1e-5f);
        float sws = sw * scale;
#pragma unroll
        for (int k = 0; k < 4; ++k) wf[c][k] = sws * conv_w[c * 4 + k];
        bf[c] = sw * (scale * (conv_b[c] - bn_mean[c]) + bn_beta[c]);
    }
    const float th0 = theta[0], th1 = theta[1], th2 = theta[2], th3 = theta[3];
    float s4, c4, s5, c5, s6, c6, s7, c7;
    __sincosf(0.5f * theta[4], &s4, &c4);
    __sincosf(0.5f * theta[5], &s5, &c5);
    __sincosf(0.5f * theta[6], &s6, &c6);
    __sincosf(0.5f * theta[7], &s7, &c7);

    auto pair_meas = [&](float xa, float xb, float tha, float thb,
                         float sE, float cE, float sF, float cF,
                         float& mA, float& mB) {
        float sA, cA, sB, cB;
        __sincosf(0.5f * (xa + tha), &sA, &cA);
        __sincosf(0.5f * (xb + thb), &sB, &cB);
        float cc = cA * cB, ss = sA * sB, cs = cA * sB, sc_ = sA * cB;
        float u0 = cE * cc - sE * ss;
        float u1 = cE * cs - sE * sc_;
        float u2 = sE * cc + cE * ss;
        float u3 = sE * cs + cE * sc_;
        float v0 = cF * u0 - sF * u1, v1 = sF * u0 + cF * u1;
        float v2 = cF * u2 - sF * u3, v3 = sF * u2 + cF * u3;
        mA = u0 * u0 + u1 * u1 - u2 * u2 - u3 * u3;
        mB = v0 * v0 - v1 * v1 + v2 * v2 - v3 * v3;
    };

    // ---- pass 1: patch math for both images ----
    unsigned qa0[4], qa1[4], qb0[4], qb1[4];
    auto pass1 = [&](const float2* px, __half* fw, unsigned* q0, unsigned* q1) {
#pragma unroll
        for (int j = 0; j < 3; ++j) {
            const int p = lane + 64 * j;
            float x00 = px[2 * j].x, x01 = px[2 * j].y;
            float x10 = px[2 * j + 1].x, x11 = px[2 * j + 1].y;
            float m0, m1, m2, m3;
            pair_meas(x00, x01, th0, th1, s4, c4, s5, c5, m0, m1);
            pair_meas(x10, x11, th2, th3, s6, c6, s7, c7, m2, m3);
            q0[j] = packh(m0, m1);
            q1[j] = packh(m2, m3);
#pragma unroll
            for (int c = 0; c < 4; ++c)
                fw[c * 196 + p] = __float2half(
                    wf[c][0] * x00 + wf[c][1] * x01 +
                    wf[c][2] * x10 + wf[c][3] * x11 + bf[c]);
        }
        if (lane < 4) {
            const int p = lane + 192;
            float x00 = px[6].x, x01 = px[6].y;
            float x10 = px[7].x, x11 = px[7].y;
            float m0, m1, m2, m3;
            pair_meas(x00, x01, th0, th1, s4, c4, s5, c5, m0, m1);
            pair_meas(x10, x11, th2, th3, s6, c6, s7, c7, m2, m3);
            q0[3] = packh(m0, m1);
            q1[3] = packh(m2, m3);
#pragma unroll
            for (int c = 0; c < 4; ++c)
                fw[c * 196 + p] = __float2half(
                    wf[c][0] * x00 + wf[c][1] * x01 +
                    wf[c][2] * x10 + wf[c][3] * x11 + bf[c]);
        }
    };
    pass1(px0, fw0, qa0, qa1);
    pass1(px1, fw1, qb0, qb1);

    WAVE_LGKM();   // cross-lane shortcut writes visible within the wave

    // ---- pass 2: add quantum feats (lane owns slots 4p..4p+3) ----
    auto pass2 = [&](__half* fw, const unsigned* q0, const unsigned* q1) {
#pragma unroll
        for (int j = 0; j < 4; ++j) {
            if (j == 3 && lane >= 4) break;
            const int p = lane + 64 * j;
            uint2 v = *(uint2*)&fw[4 * p];
            __half2 a0 = __builtin_bit_cast(__half2, v.x);
            __half2 a1 = __builtin_bit_cast(__half2, v.y);
            a0 = __hadd2(a0, __builtin_bit_cast(__half2, q0[j]));
            a1 = __hadd2(a1, __builtin_bit_cast(__half2, q1[j]));
            v.x = __builtin_bit_cast(unsigned, a0);
            v.y = __builtin_bit_cast(unsigned, a1);
            *(uint2*)&fw[4 * p] = v;
        }
    };
    pass2(fw0, qa0, qa1);
    pass2(fw1, qb0, qb1);

    __syncthreads();   // lw staging complete + own pass2 drained (waitcnt+barrier)

    // ---- joint matmul for both images: lane = k*6 + c ----
    float acc0 = 0.f, acc1 = 0.f;
    if (lane < 60) {
        const int k = lane / 6, c = lane - k * 6;
        const int start = c * 136;
        const int nit = (c == 5) ? 13 : 17;
        const uint4* wp = (const uint4*)&lw[k * LWS + start];
        const uint4* f0 = (const uint4*)&fw0[start];
        const uint4* f1 = (const uint4*)&fw1[start];
        for (int i = 0; i < nit; ++i) {
            uint4 w = wp[i], a = f0[i], b = f1[i];
            acc0 = dot2h(a.x, w.x, acc0);
            acc0 = dot2h(a.y, w.y, acc0);
            acc0 = dot2h(a.z, w.z, acc0);
            acc0 = dot2h(a.w, w.w, acc0);
            acc1 = dot2h(b.x, w.x, acc1);
            acc1 = dot2h(b.y, w.y, acc1);
            acc1 = dot2h(b.z, w.z, acc1);
            acc1 = dot2h(b.w, w.w, acc1);
        }
    }

    // ---- reduce over the 6 chunk lanes (valid at lane = 6k) ----
    float s1a = acc0 + __shfl_down(acc0, 1);
    float s2a = s1a + __shfl_down(s1a, 2);
    float ta  = s2a + __shfl_down(s1a, 4);
    float s1b = acc1 + __shfl_down(acc1, 1);
    float s2b = s1b + __shfl_down(s1b, 2);
    float tb  = s2b + __shfl_down(s1b, 4);

    float logit0 = 0.f, logit1 = 0.f;
    if (lane < 60 && lane % 6 == 0) {
        const float bk = lin_b[lane / 6];
        logit0 = (ta + bk) * ls;
        logit1 = (tb + bk) * ls;
    }

    // ---- redundant all-lane softmax, lanes 0-9 store ----
    float m0 = -1e30f, m1 = -1e30f;
#pragma unroll
    for (int kk = 0; kk < 10; ++kk) {
        m0 = fmaxf(m0, __shfl(logit0, kk * 6));
        m1 = fmaxf(m1, __shfl(logit1, kk * 6));
    }
    float ss0 = 0.f, ss1 = 0.f;
#pragma unroll
    for (int kk = 0; kk < 10; ++kk) {
        ss0 += __expf(__shfl(logit0, kk * 6) - m0);
        ss1 += __expf(__shfl(logit1, kk * 6) - m1);
    }
    const float lse0 = m0 + __logf(ss0);
    const float lse1 = m1 + __logf(ss1);
    const float lg0 = __shfl(logit0, 6 * lane);
    const float lg1 = __shfl(logit1, 6 * lane);
    if (lane < 10) {
        out[(size_t)img0 * 10 + lane] = lg0 - lse0;
        out[(size_t)img1 * 10 + lane] = lg1 - lse1;
    }
}

extern "C" void kernel_launch(void* const* d_in, const int* in_sizes, int n_in,
                              void* d_out, int out_size, void* d_ws, size_t ws_size,
                              hipStream_t stream) {
    const float* x         = (const float*)d_in[0];
    const float* conv_w    = (const float*)d_in[1];
    const float* conv_b    = (const float*)d_in[2];
    const float* bn_gamma  = (const float*)d_in[3];
    const float* bn_beta   = (const float*)d_in[4];
    const float* bn_mean   = (const float*)d_in[5];
    const float* bn_var    = (const float*)d_in[6];
    const float* sw        = (const float*)d_in[7];
    const float* theta     = (const float*)d_in[8];
    const float* lin_w     = (const float*)d_in[9];
    const float* lin_b     = (const float*)d_in[10];
    const float* log_scale = (const float*)d_in[11];
    float* out = (float*)d_out;

    const int B = in_sizes[0] / 784;                 // 8192
    dim3 grid(B / (WVS * 2)), block(BLOCK);          // 512 blocks
    hipLaunchKernelGGL(quanv_fused3, grid, block, 0, stream,
                       x, conv_w, conv_b, bn_gamma, bn_beta, bn_mean, bn_var,
                       sw, theta, lin_w, lin_b, log_scale, out);
}